// Round 5
// baseline (864.171 us; speedup 1.0000x reference)
//
#include <hip/hip_runtime.h>
#include <hip/hip_bf16.h>

// ---------------- problem constants ----------------
#define Bz   32
#define Nn_  577
#define Np   640                    // 577 padded to 5*128
#define Cc   768
#define Hh   3072
#define Mrows (Bz * Nn_)            // 18464
#define OUT_X (Mrows * Cc)          // 14,180,352 floats
#define SCALE 0.03608439182435161f  // 768^-0.5

typedef unsigned short ushort_t;
typedef short short8 __attribute__((ext_vector_type(8)));
typedef float f32x4 __attribute__((ext_vector_type(4)));

__device__ __forceinline__ ushort_t f2b(float f) {
    __hip_bfloat16 h = __float2bfloat16(f);
    return *reinterpret_cast<ushort_t*>(&h);
}

// fast exact-GELU: erf via Abramowitz-Stegun 7.1.26 (|err| <= 1.5e-7)
__device__ __forceinline__ float gelu_f(float v) {
    float z  = v * 0.70710678118654752f;
    float az = fabsf(z);
    float t_ = __builtin_amdgcn_rcpf(1.f + 0.3275911f * az);
    float y  = t_ * (0.254829592f + t_ * (-0.284496736f + t_ * (1.421413741f +
               t_ * (-1.453152027f + t_ * 1.061405429f))));
    float e  = __expf(-az * az);
    float er = 1.f - y * e;
    er = (z < 0.f) ? -er : er;
    return 0.5f * v * (1.f + er);
}

// ---------------- async global->LDS (16B per lane) ----------------
__device__ __forceinline__ void gl16(const ushort_t* g, ushort_t* l) {
    __builtin_amdgcn_global_load_lds(
        (const __attribute__((address_space(1))) void*)g,
        (__attribute__((address_space(3))) void*)l, 16, 0, 0);
}

// ---------------- block reduction helpers (256-thread blocks) ----------------
__device__ __forceinline__ float bsum(float v, float* sm) {
    #pragma unroll
    for (int o = 32; o > 0; o >>= 1) v += __shfl_down(v, o, 64);
    int lane = threadIdx.x & 63, wid = threadIdx.x >> 6;
    if (lane == 0) sm[wid] = v;
    __syncthreads();
    float r = sm[0] + sm[1] + sm[2] + sm[3];
    __syncthreads();
    return r;
}
__device__ __forceinline__ float bmax(float v, float* sm) {
    #pragma unroll
    for (int o = 32; o > 0; o >>= 1) v = fmaxf(v, __shfl_down(v, o, 64));
    int lane = threadIdx.x & 63, wid = threadIdx.x >> 6;
    if (lane == 0) sm[wid] = v;
    __syncthreads();
    float r = fmaxf(fmaxf(sm[0], sm[1]), fmaxf(sm[2], sm[3]));
    __syncthreads();
    return r;
}

// ---------------- fp32 -> bf16 convert ----------------
__global__ void cvt_kernel(const float* __restrict__ in, ushort_t* __restrict__ out, int n) {
    int i = blockIdx.x * 256 + threadIdx.x;
    if (i < n) out[i] = f2b(in[i]);
}

// ---------------- LayerNorm: fp32 in, bf16 out ----------------
__global__ void ln_bf16(const float* __restrict__ x, const float* __restrict__ w,
                        const float* __restrict__ b, ushort_t* __restrict__ out) {
    __shared__ float sm[8];
    long long row = blockIdx.x;
    const float* xr = x + row * Cc;
    float v[3]; float s = 0.f;
    #pragma unroll
    for (int i = 0; i < 3; ++i) { v[i] = xr[threadIdx.x + i * 256]; s += v[i]; }
    float mu = bsum(s, sm) * (1.f / (float)Cc);
    float sq = 0.f;
    #pragma unroll
    for (int i = 0; i < 3; ++i) { float d = v[i] - mu; sq += d * d; }
    float var = bsum(sq, sm + 4) * (1.f / (float)Cc);
    float inv = rsqrtf(var + 1e-5f);
    ushort_t* orow = out + row * Cc;
    #pragma unroll
    for (int i = 0; i < 3; ++i) {
        int c = threadIdx.x + i * 256;
        orow[c] = f2b((v[i] - mu) * inv * w[c] + b[c]);
    }
}

// ---------------- softmax: fp32 Sf (ld 640, 577 valid) -> bf16 Sb (zero-padded) + tok ----------------
__global__ void softmax_bf16(const float* __restrict__ Sf, ushort_t* __restrict__ Sb,
                             float* __restrict__ tok) {
    __shared__ float sm[8];
    long long row = blockIdx.x;
    int b_l = (int)(row / Nn_), r = (int)(row - (long long)b_l * Nn_);
    const float* src = Sf + row * Np;
    ushort_t* dst = Sb + row * Np;
    float v[3]; float mx = -1e30f;
    #pragma unroll
    for (int i = 0; i < 3; ++i) {
        int c = threadIdx.x + i * 256;
        v[i] = (c < Nn_) ? src[c] : -1e30f;
        mx = fmaxf(mx, v[i]);
    }
    mx = bmax(mx, sm);
    float s = 0.f;
    #pragma unroll
    for (int i = 0; i < 3; ++i) {
        int c = threadIdx.x + i * 256;
        v[i] = (c < Nn_) ? expf(v[i] - mx) : 0.f;
        s += v[i];
    }
    s = bsum(s, sm + 4);
    float inv = 1.f / s;
    #pragma unroll
    for (int i = 0; i < 3; ++i) {
        int c = threadIdx.x + i * 256;
        float p = v[i] * inv;
        if (c < Np) dst[c] = (c < Nn_) ? f2b(p) : (ushort_t)0;
        if (r == 0 && c >= 1 && c < Nn_) tok[(long long)b_l * 576 + (c - 1)] = p;
    }
}

// ---------------- epilogue selectors ----------------
#define EPS_STORE  0
#define EPS_X2     1
#define EPS_GELU   2
#define EPS_ADD    3
#define EPS_QKV    4

// =====================================================================
// 128x128 / BK=32 / 4-wave kernel (2-phase dbuf) — kept for batched QK^T / PV
// =====================================================================
#define MM_STAGE(AS, BS, k0) do {            \
    gl16(Ag0 + (k0), &AS[e0]);               \
    gl16(Ag1 + (k0), &AS[e1]);               \
    gl16(Bg0 + (k0), &BS[e0]);               \
    gl16(Bg1 + (k0), &BS[e1]);               \
} while (0)

#define MM_COMPUTE(AS, BS) do {                                             \
    short8 af[4], bfr[4];                                                   \
    _Pragma("unroll")                                                       \
    for (int i = 0; i < 4; ++i) {                                           \
        int r = wr + i * 16 + fr;                                           \
        af[i] = *(const short8*)&AS[r * 32 + ((kq ^ (r & 3)) << 3)];        \
    }                                                                       \
    _Pragma("unroll")                                                       \
    for (int j = 0; j < 4; ++j) {                                           \
        int r = wc + j * 16 + fr;                                           \
        bfr[j] = *(const short8*)&BS[r * 32 + ((kq ^ (r & 3)) << 3)];       \
    }                                                                       \
    _Pragma("unroll")                                                       \
    for (int i = 0; i < 4; ++i)                                             \
        _Pragma("unroll")                                                   \
        for (int j = 0; j < 4; ++j)                                         \
            acc[i][j] = __builtin_amdgcn_mfma_f32_16x16x32_bf16(            \
                af[i], bfr[j], acc[i][j], 0, 0, 0);                         \
} while (0)

template<int EPI, typename OutT>
__global__ __launch_bounds__(256)
void mm_bf16(const ushort_t* __restrict__ A, long long sAb, int lda, int M,
             const ushort_t* __restrict__ B, long long sBb, int ldb, int Nv,
             const float* __restrict__ bias,
             OutT* __restrict__ O, long long sOb, int ldo,
             int K, float alpha,
             ushort_t* __restrict__ qQ, ushort_t* __restrict__ qK, ushort_t* __restrict__ qV)
{
    __shared__ __align__(16) ushort_t As0[128 * 32];
    __shared__ __align__(16) ushort_t As1[128 * 32];
    __shared__ __align__(16) ushort_t Bs0[128 * 32];
    __shared__ __align__(16) ushort_t Bs1[128 * 32];
    const int z = blockIdx.z;
    A += (long long)z * sAb; B += (long long)z * sBb;
    if (O) O += (long long)z * sOb;
    const int n0 = blockIdx.x * 128;
    const int m0 = blockIdx.y * 128;
    const int tid = threadIdx.x;
    const int lane = tid & 63;
    const int wv = tid >> 6;
    const int wr = (wv >> 1) << 6;
    const int wc = (wv & 1) << 6;
    const int fr = lane & 15;
    const int kq = lane >> 4;

    const int e0 = tid * 8, e1 = 2048 + tid * 8;
    const int ra0 = e0 >> 5, qa0 = (((e0 & 31) >> 3) ^ (ra0 & 3)) << 3;
    const int ra1 = e1 >> 5, qa1 = (((e1 & 31) >> 3) ^ (ra1 & 3)) << 3;
    const ushort_t* Ag0 = A + (long long)min(m0 + ra0, M - 1) * lda + qa0;
    const ushort_t* Ag1 = A + (long long)min(m0 + ra1, M - 1) * lda + qa1;
    const ushort_t* Bg0 = B + (long long)min(n0 + ra0, Nv - 1) * ldb + qa0;
    const ushort_t* Bg1 = B + (long long)min(n0 + ra1, Nv - 1) * ldb + qa1;

    f32x4 acc[4][4] = {};
    const int nt = K >> 5;

    MM_STAGE(As0, Bs0, 0);
    __syncthreads();

    for (int t = 0; t < nt; t += 2) {
        MM_STAGE(As1, Bs1, (t + 1) << 5);
        MM_COMPUTE(As0, Bs0);
        __syncthreads();
        if (t + 2 < nt) MM_STAGE(As0, Bs0, (t + 2) << 5);
        MM_COMPUTE(As1, Bs1);
        __syncthreads();
    }

    #pragma unroll
    for (int i = 0; i < 4; ++i) {
        int mb = m0 + wr + i * 16 + (lane >> 4) * 4;
        #pragma unroll
        for (int j = 0; j < 4; ++j) {
            int n = n0 + wc + j * 16 + fr;
            if (n >= Nv) continue;
            f32x4 v4 = acc[i][j];
            #pragma unroll
            for (int r = 0; r < 4; ++r) {
                int m = mb + r;
                if (m >= M) continue;
                float v = v4[r] * alpha;
                if constexpr (EPI == EPS_QKV) {
                    int b_l = m / Nn_, rr = m - b_l * Nn_;
                    if (n < Cc)            qQ[(long long)m * Cc + n] = f2b(v);
                    else if (n < 2 * Cc)   qK[(long long)m * Cc + (n - Cc)] = f2b(v);
                    else                   qV[((long long)b_l * Cc + (n - 2 * Cc)) * Np + rr] = f2b(v);
                } else if constexpr (EPI == EPS_ADD) {
                    if (bias) v += bias[n];
                    long long oi = (long long)m * ldo + n;
                    O[oi] += v;
                } else {
                    if (bias) v += bias[n];
                    if constexpr (EPI == EPS_X2) v *= 2.f;
                    if constexpr (EPI == EPS_GELU) v = gelu_f(v);
                    long long oi = (long long)m * ldo + n;
                    if constexpr (sizeof(OutT) == 2) O[oi] = (OutT)f2b(v);
                    else                             O[oi] = (OutT)v;
                }
            }
        }
    }
}

// =====================================================================
// 256x256 / BK=64 / 8-wave 8-phase GEMM — faithful m201-style derivation.
// Halves are M/N-HALVES: A0 = A rows [0,128), A1 = [128,256), B0/B1 same
// for B; each half = 128 rows x 64 k bf16 = 16KB, double-buffered -> 128KB.
// Each wave (2M x 4N decomp) reads exactly ONE A-half (wv>>2) and ONE
// B-half ((wv&3)>>1).
// LDS line = one row (128B = 8 x 16B chunks); physical chunk = logical ^
// (row&7) (involution, applied on the global-source side; gl16 writes
// linearly). Conflict-balanced ds_read_b128 (verified 0-conflict class).
// Schedule per K-tile t (4 phases, P = t&1):
//   p0: ds_read A kk0 (8) + B kk0 (4) | stage B0(t+1) | lgkmcnt(8) | bar |
//       lgkmcnt(0) | MFMA mf0-3 x kk0 | bar
//   p1: ds_read A kk1 (8)             | stage B1(t+1) | bar | lgkmcnt(0) |
//       MFMA mf4-7 x kk0 | bar
//   p2: ds_read B kk1 (4)             | stage A0(t+2) | bar | lgkmcnt(0) |
//       MFMA mf0-3 x kk1 | bar
//   p3: (no reads)                    | stage A1(t+2) | vmcnt(4) | bar |
//       MFMA mf4-7 x kk1 | bar
// Liveness proof: A[P] LDS dead after p1 reads; overwrite (A of t+2) staged
// p2/p3 — after p1's closing barrier. B[P] dead after p2; overwrite staged
// next tile's p0/p1. vmcnt(4) at p3 confirms ALL of tile t+1 (8 oldest of
// 12 outstanding) while leaving t+2's A-halves (4 loads) in flight — halves
// get 4-6 phases of flight; never drain mid-loop (tail: vmcnt(0) at
// t >= nt-2). Prologue stages 6 halves (t0 all + t1.A0/A1), vmcnt(4)
// confirms t0.
// =====================================================================
#define STG_A0(Ts) do { if ((Ts) < nt) { int Pd = (Ts) & 1; int ko = (Ts) * 64; \
    gl16(gA00 + ko, &HA[Pd][0][tid * 8]);                                       \
    gl16(gA01 + ko, &HA[Pd][0][tid * 8 + 4096]); } } while (0)
#define STG_A1(Ts) do { if ((Ts) < nt) { int Pd = (Ts) & 1; int ko = (Ts) * 64; \
    gl16(gA10 + ko, &HA[Pd][1][tid * 8]);                                       \
    gl16(gA11 + ko, &HA[Pd][1][tid * 8 + 4096]); } } while (0)
#define STG_B0(Ts) do { if ((Ts) < nt) { int Pd = (Ts) & 1; int ko = (Ts) * 64; \
    gl16(gB00 + ko, &HB[Pd][0][tid * 8]);                                       \
    gl16(gB01 + ko, &HB[Pd][0][tid * 8 + 4096]); } } while (0)
#define STG_B1(Ts) do { if ((Ts) < nt) { int Pd = (Ts) & 1; int ko = (Ts) * 64; \
    gl16(gB10 + ko, &HB[Pd][1][tid * 8]);                                       \
    gl16(gB11 + ko, &HB[Pd][1][tid * 8 + 4096]); } } while (0)

#define RDA8(dst, ckc) do {                                              \
    _Pragma("unroll")                                                    \
    for (int mf_ = 0; mf_ < 8; ++mf_)                                    \
        dst[mf_] = *(const short8*)&HA[P][ha][(mf_ * 16 + fr) * 64 + (ckc)]; \
} while (0)
#define RDB4(dst, ckc) do {                                              \
    _Pragma("unroll")                                                    \
    for (int nf_ = 0; nf_ < 4; ++nf_)                                    \
        dst[nf_] = *(const short8*)&HB[P][hbh][(nb + nf_ * 16 + fr) * 64 + (ckc)]; \
} while (0)

#define MM16(mbase, AF, BF) do {                                         \
    __builtin_amdgcn_s_setprio(1);                                       \
    _Pragma("unroll")                                                    \
    for (int i_ = 0; i_ < 4; ++i_)                                       \
        _Pragma("unroll")                                                \
        for (int j_ = 0; j_ < 4; ++j_)                                   \
            acc[(mbase) + i_][j_] = __builtin_amdgcn_mfma_f32_16x16x32_bf16( \
                AF[(mbase) + i_], BF[j_], acc[(mbase) + i_][j_], 0, 0, 0);   \
    __builtin_amdgcn_s_setprio(0);                                       \
} while (0)

#define BAR()  __builtin_amdgcn_s_barrier()
#define LGK0() do { asm volatile("s_waitcnt lgkmcnt(0)" ::: "memory");   \
                    __builtin_amdgcn_sched_barrier(0); } while (0)

template<int EPI, typename OutT>
__global__ __launch_bounds__(512, 2)
void mm256(const ushort_t* __restrict__ A, int lda, int M,
           const ushort_t* __restrict__ B, int ldb, int Nv,
           const float* __restrict__ bias,
           OutT* __restrict__ O, int ldo,
           int K, float alpha,
           ushort_t* __restrict__ qQ, ushort_t* __restrict__ qK, ushort_t* __restrict__ qV)
{
    __shared__ __align__(16) ushort_t HA[2][2][8192];   // [dbuf][M-half] 16KB each
    __shared__ __align__(16) ushort_t HB[2][2][8192];   // [dbuf][N-half]

    // T1: bijective XCD-aware remap (m204 formula)
    const int nwg = gridDim.x * gridDim.y;
    const int flat = blockIdx.y * gridDim.x + blockIdx.x;
    const int qq = nwg >> 3, rr8 = nwg & 7;
    const int xcd = flat & 7, idx = flat >> 3;
    const int wg = (xcd < rr8 ? xcd * (qq + 1) : rr8 * (qq + 1) + (xcd - rr8) * qq) + idx;
    const int bx = wg % gridDim.x, by = wg / gridDim.x;

    const int n0 = bx * 256, m0 = by * 256;
    const int tid = (int)threadIdx.x;
    const int lane = tid & 63;
    const int wv = tid >> 6;            // 0..7
    const int wm  = (wv >> 2) * 128;    // wave M-offset (= its A-half * 128)
    const int wn  = (wv & 3) * 64;      // wave N-offset
    const int ha  = wv >> 2;            // A half index
    const int hbh = (wv & 3) >> 1;      // B half index
    const int nb  = wn & 127;           // n-base within B half (0 or 64)
    const int fr = lane & 15;
    const int kq = lane >> 4;
    const int fx = fr & 7;
    const int ck0 = ((0 + kq) ^ fx) * 8;   // kk0 chunk (ushort offset in row)
    const int ck1 = ((4 + kq) ^ fx) * 8;   // kk1 chunk

    // staging: thread covers slots s0=tid, s1=tid+512 of a 16KB half.
    // slot s: row = s>>3 (s1 -> row+64), logical chunk c = (s&7) ^ (row&7)
    // (row&7 identical for s0/s1 since 64 ≡ 0 mod 8).
    const int r0 = tid >> 3;                 // 0..63
    const int c0 = (tid & 7) ^ (r0 & 7);
    const ushort_t* gA00 = A + (long long)min(m0 +       r0, M - 1) * lda + c0 * 8;
    const ushort_t* gA01 = A + (long long)min(m0 +  64 + r0, M - 1) * lda + c0 * 8;
    const ushort_t* gA10 = A + (long long)min(m0 + 128 + r0, M - 1) * lda + c0 * 8;
    const ushort_t* gA11 = A + (long long)min(m0 + 192 + r0, M - 1) * lda + c0 * 8;
    const ushort_t* gB00 = B + (long long)min(n0 +       r0, Nv - 1) * ldb + c0 * 8;
    const ushort_t* gB01 = B + (long long)min(n0 +  64 + r0, Nv - 1) * ldb + c0 * 8;
    const ushort_t* gB10 = B + (long long)min(n0 + 128 + r0, Nv - 1) * ldb + c0 * 8;
    const ushort_t* gB11 = B + (long long)min(n0 + 192 + r0, Nv - 1) * ldb + c0 * 8;

    f32x4 acc[8][4] = {};
    const int nt = K >> 6;              // K % 64 == 0 at all call sites (>= 12)

    // prologue: 6 halves (t0 complete + t1.A0/A1); confirm t0 (8 oldest of 12)
    STG_A0(0); STG_A1(0); STG_B0(0); STG_B1(0); STG_A0(1); STG_A1(1);
    asm volatile("s_waitcnt vmcnt(4)" ::: "memory");
    __builtin_amdgcn_sched_barrier(0);
    BAR();

    for (int t = 0; t < nt; ++t) {
        const int P = t & 1;
        short8 a0[8], a1[8], b0[4], b1[4];

        // ---- phase 0: A kk0 (8) + B kk0 (4); stage B0(t+1)
        RDA8(a0, ck0); RDB4(b0, ck0);
        STG_B0(t + 1);
        asm volatile("s_waitcnt lgkmcnt(8)" ::: "memory");
        __builtin_amdgcn_sched_barrier(0);
        BAR(); LGK0();
        MM16(0, a0, b0);
        BAR();

        // ---- phase 1: A kk1 (8); stage B1(t+1)
        RDA8(a1, ck1);
        STG_B1(t + 1);
        BAR(); LGK0();
        MM16(4, a0, b0);
        BAR();

        // ---- phase 2: B kk1 (4); stage A0(t+2)  (A[P] LDS dead after p1)
        RDB4(b1, ck1);
        STG_A0(t + 2);
        BAR(); LGK0();
        MM16(0, a1, b1);
        BAR();

        // ---- phase 3: stage A1(t+2); counted confirm of tile t+1
        STG_A1(t + 2);
        if (t + 2 < nt) { asm volatile("s_waitcnt vmcnt(4)" ::: "memory"); }
        else            { asm volatile("s_waitcnt vmcnt(0)" ::: "memory"); }
        __builtin_amdgcn_sched_barrier(0);
        BAR(); LGK0();
        MM16(4, a1, b1);
        BAR();
    }

    // epilogue: m = m0 + wm + mf*16 + (lane>>4)*4 + r ; n = n0 + wn + nf*16 + fr
    #pragma unroll
    for (int mf = 0; mf < 8; ++mf) {
        int mb = m0 + wm + mf * 16 + (lane >> 4) * 4;
        #pragma unroll
        for (int nf = 0; nf < 4; ++nf) {
            int n = n0 + wn + nf * 16 + fr;
            if (n >= Nv) continue;
            f32x4 v4 = acc[mf][nf];
            #pragma unroll
            for (int r = 0; r < 4; ++r) {
                int m = mb + r;
                if (m >= M) continue;
                float v = v4[r] * alpha;
                if constexpr (EPI == EPS_QKV) {
                    int b_l = m / Nn_, rq = m - b_l * Nn_;
                    if (n < Cc)            qQ[(long long)m * Cc + n] = f2b(v);
                    else if (n < 2 * Cc)   qK[(long long)m * Cc + (n - Cc)] = f2b(v);
                    else                   qV[((long long)b_l * Cc + (n - 2 * Cc)) * Np + rq] = f2b(v);
                } else if constexpr (EPI == EPS_ADD) {
                    if (bias) v += bias[n];
                    long long oi = (long long)m * ldo + n;
                    O[oi] += v;          // single owner per output
                } else {
                    if (bias) v += bias[n];
                    if constexpr (EPI == EPS_X2) v *= 2.f;
                    if constexpr (EPI == EPS_GELU) v = gelu_f(v);
                    long long oi = (long long)m * ldo + n;
                    if constexpr (sizeof(OutT) == 2) O[oi] = (OutT)f2b(v);
                    else                             O[oi] = (OutT)v;
                }
            }
        }
    }
}

// ---------------- launcher ----------------
extern "C" void kernel_launch(void* const* d_in, const int* in_sizes, int n_in,
                              void* d_out, int out_size, void* d_ws, size_t ws_size,
                              hipStream_t stream) {
    const float* x      = (const float*)d_in[0];
    const float* n1w    = (const float*)d_in[1];
    const float* n1b    = (const float*)d_in[2];
    const float* qkv_w  = (const float*)d_in[3];
    const float* proj_w = (const float*)d_in[4];
    const float* proj_b = (const float*)d_in[5];
    const float* n2w    = (const float*)d_in[6];
    const float* n2b    = (const float*)d_in[7];
    const float* fc1w   = (const float*)d_in[8];
    const float* fc1b   = (const float*)d_in[9];
    const float* fc2w   = (const float*)d_in[10];
    const float* fc2b   = (const float*)d_in[11];
    float* out = (float*)d_out;
    float* x2  = out;
    float* tok = out + OUT_X;

    // ---- persistent bf16 weights at ws start ----
    char* ws = (char*)d_ws;
    const long long nWq = (long long)3 * Cc * Cc;
    const long long nWp = (long long)Cc * Cc;
    const long long nW1 = (long long)Hh * Cc;
    const long long nW2 = (long long)Cc * Hh;
    ushort_t* wq = (ushort_t*)ws;
    ushort_t* wp = wq + nWq;
    ushort_t* w1 = wp + nWp;
    ushort_t* w2 = w1 + nW1;
    const long long WBYTES = 2 * (nWq + nWp + nW1 + nW2); // 14,155,776
    char* dyn = ws + WBYTES;
    long long avail = (long long)ws_size - WBYTES;

    // ---- adaptive sizes (prefer no chunking: G=32, CH=full) ----
    const long long perG = 3LL * Nn_ * Cc * 2 + (long long)Cc * Np * 2
                         + (long long)Nn_ * Np * 4 + (long long)Nn_ * Np * 2;
    int G = 1;
    { const int o[6] = {32, 16, 8, 4, 2, 1};
      for (int i = 0; i < 6; ++i) if ((long long)o[i] * perG <= avail) { G = o[i]; break; } }
    int CH = Nn_;
    { const int o[6] = {32, 16, 8, 4, 2, 1};
      for (int i = 0; i < 6; ++i) if ((long long)o[i] * Nn_ * (Cc + Hh) * 2 <= avail) { CH = o[i] * Nn_; break; } }

    // phase A layout: hbf/Yt | Q | Kb | Vt | Sf | Sb
    ushort_t* hbf = (ushort_t*)dyn;
    ushort_t* Q   = hbf + (long long)G * Nn_ * Cc;
    ushort_t* Kb  = Q   + (long long)G * Nn_ * Cc;
    ushort_t* Vt  = Kb  + (long long)G * Nn_ * Cc;
    float*    Sf  = (float*)(Vt + (long long)G * Cc * Np);
    ushort_t* Sb  = (ushort_t*)(Sf + (long long)G * Nn_ * Np);
    ushort_t* Yt  = hbf;
    // phase B layout: g | t
    ushort_t* g = (ushort_t*)dyn;
    ushort_t* t = g + (long long)CH * Cc;

    // ---- weight conversion (every call; ws is re-poisoned) ----
    cvt_kernel<<<(int)((nWq + 255) / 256), 256, 0, stream>>>(qkv_w, wq, (int)nWq);
    cvt_kernel<<<(int)((nWp + 255) / 256), 256, 0, stream>>>(proj_w, wp, (int)nWp);
    cvt_kernel<<<(int)((nW1 + 255) / 256), 256, 0, stream>>>(fc1w, w1, (int)nW1);
    cvt_kernel<<<(int)((nW2 + 255) / 256), 256, 0, stream>>>(fc2w, w2, (int)nW2);

    // ================= phase A: attention per group of G batches =================
    for (int b0 = 0; b0 < Bz; b0 += G) {
        const int MR = G * Nn_;
        const int myM256 = (MR + 255) / 256;

        ln_bf16<<<MR, 256, 0, stream>>>(x + (long long)b0 * Nn_ * Cc, n1w, n1b, hbf);

        // qkv: (MR x 2304 x 768), scatter to Q | Kb | Vt  (8-phase 256-tile)
        mm256<EPS_QKV, float><<<dim3(9, myM256, 1), 512, 0, stream>>>(
            hbf, Cc, MR, wq, Cc, 3 * Cc, nullptr,
            (float*)nullptr, Cc, Cc, 1.f, Q, Kb, Vt);

        // Sf = scale * Q @ K^T per batch (577x577 valid, ld 640) — 128-tile batched
        mm_bf16<EPS_STORE, float><<<dim3(5, 5, G), 256, 0, stream>>>(
            Q, (long long)Nn_ * Cc, Cc, Nn_, Kb, (long long)Nn_ * Cc, Cc, Nn_, nullptr,
            Sf, (long long)Nn_ * Np, Np, Cc, SCALE, nullptr, nullptr, nullptr);

        softmax_bf16<<<MR, 256, 0, stream>>>(Sf, Sb, tok + (long long)b0 * 576);

        // Yt[c, n] = sum_m Vt[c, m] * Sb[n, m]  (M=768, N=577 valid, K=640) — 128-tile batched
        mm_bf16<EPS_STORE, ushort_t><<<dim3(5, 6, G), 256, 0, stream>>>(
            Vt, (long long)Cc * Np, Np, Cc, Sb, (long long)Nn_ * Np, Np, Nn_, nullptr,
            Yt, (long long)Cc * Nn_, Nn_, Np, 1.f, nullptr, nullptr, nullptr);

        // x2 = 2*(Yt_flat @ proj_w^T + proj_b) -> d_out rows of group (fp32)
        mm256<EPS_X2, float><<<dim3(3, myM256, 1), 512, 0, stream>>>(
            Yt, Cc, MR, wp, Cc, Cc, proj_b,
            x2 + (long long)b0 * Nn_ * Cc, Cc, Cc, 1.f, nullptr, nullptr, nullptr);
    }

    // ================= phase B: MLP per chunk of CH rows =================
    for (int c0 = 0; c0 < Mrows; c0 += CH) {
        const int cn = (Mrows - c0 < CH) ? (Mrows - c0) : CH;
        const int myC256 = (cn + 255) / 256;

        ln_bf16<<<cn, 256, 0, stream>>>(x2 + (long long)c0 * Cc, n2w, n2b, g);

        // t = gelu(g @ fc1^T + b1)  (cn x 3072 x 768), bf16
        mm256<EPS_GELU, ushort_t><<<dim3(12, myC256, 1), 512, 0, stream>>>(
            g, Cc, cn, w1, Cc, Hh, fc1b,
            t, Hh, Cc, 1.f, nullptr, nullptr, nullptr);

        // x2 += t @ fc2^T + b2  (cn x 768 x 3072), plain += epilogue
        mm256<EPS_ADD, float><<<dim3(3, myC256, 1), 512, 0, stream>>>(
            t, Hh, cn, w2, Hh, Cc, fc2b,
            x2 + (long long)c0 * Cc, Cc, Hh, 1.f, nullptr, nullptr, nullptr);
    }
}